// Round 2
// baseline (245.568 us; speedup 1.0000x reference)
//
#include <hip/hip_runtime.h>

#define PH 7
#define PW 7
#define SSCALE 0.0625f
#define SR 2
#define CC 256
#define HH 200
#define WW 200

#define CPC 4            // channels per block
#define TH_MAX 40        // max tile rows (roi span <= 40)
#define PITCH 41         // +1 pad vs 40 to break power-of-2 bank strides
#define TILE (TH_MAX * PITCH)

__global__ __launch_bounds__(256) void roi_align_lds(
    const float* __restrict__ features, const float* __restrict__ rois,
    float* __restrict__ out)
{
    __shared__ float tile[CPC * TILE];   // 4 * 1640 * 4B = 26.2 KB

    const int n  = blockIdx.x;           // roi index
    const int c0 = blockIdx.y * CPC;     // first channel of chunk

    // ---- roi params (all threads compute identically; rois loads broadcast) ----
    const float* r = rois + (size_t)n * 5;
    const int   b  = (int)r[0];
    const float x1 = r[1] * SSCALE;
    const float y1 = r[2] * SSCALE;
    const float x2 = r[3] * SSCALE;
    const float y2 = r[4] * SSCALE;

    const float roi_w = fmaxf(x2 - x1, 1.0f);
    const float roi_h = fmaxf(y2 - y1, 1.0f);
    const float bin_w = roi_w * (1.0f / PW);
    const float bin_h = roi_h * (1.0f / PH);

    // sample positions run from +0.25*bin to +6.75*bin past (x1,y1)
    const float yA = y1 + 0.25f * bin_h, yB = y1 + 6.75f * bin_h;
    const float xA = x1 + 0.25f * bin_w, xB = x1 + 6.75f * bin_w;

    int row0 = min((int)floorf(fmaxf(yA, 0.0f)), HH - 1);
    int rowL = min((int)floorf(fmaxf(yB, 0.0f)), HH - 1);
    int row1 = min(rowL + 1, HH - 1);
    int th   = min(row1 - row0 + 1, TH_MAX);

    int col0 = min((int)floorf(fmaxf(xA, 0.0f)), WW - 1);
    int colL = min((int)floorf(fmaxf(xB, 0.0f)), WW - 1);
    int col1 = min(colL + 1, WW - 1);
    int tw   = min(col1 - col0 + 1, TH_MAX);

    // ---- stage footprint for CPC channels into LDS (coalesced rows) ----
    const int per   = th * tw;
    const int total = CPC * per;
    const float* fb = features + (((size_t)b * CC + c0) * HH + row0) * WW + col0;

    for (int e = threadIdx.x; e < total; e += 256) {
        int ch  = e / per;
        int rem = e - ch * per;
        int rr  = rem / tw;
        int cc  = rem - rr * tw;
        tile[ch * TILE + rr * PITCH + cc] =
            fb[(size_t)ch * (HH * WW) + rr * WW + cc];
    }
    __syncthreads();

    // ---- compute 4 channels x 49 outputs from LDS ----
    const int t = threadIdx.x;
    if (t < CPC * (PH * PW)) {
        int ch = t / (PH * PW);
        int p  = t - ch * (PH * PW);
        int ph = p / PW;
        int pw = p - ph * PW;

        const float* tch = &tile[ch * TILE];

        float acc = 0.0f;
        #pragma unroll
        for (int iy = 0; iy < SR; ++iy) {
            float y  = y1 + ((float)ph + ((float)iy + 0.5f) * (1.0f / SR)) * bin_h;
            bool  vy = (y >= -1.0f) && (y <= (float)HH);
            float cy = fmaxf(y, 0.0f);
            int   yl = min((int)floorf(cy), HH - 1);
            int   yh = min(yl + 1, HH - 1);
            float fy = (yl >= HH - 1) ? 0.0f : (cy - (float)yl);
            float hy = 1.0f - fy, ly = fy;
            int ry0 = yl - row0, ry1 = yh - row0;

            #pragma unroll
            for (int ix = 0; ix < SR; ++ix) {
                float x  = x1 + ((float)pw + ((float)ix + 0.5f) * (1.0f / SR)) * bin_w;
                bool  vx = (x >= -1.0f) && (x <= (float)WW);
                float cx = fmaxf(x, 0.0f);
                int   xl = min((int)floorf(cx), WW - 1);
                int   xh = min(xl + 1, WW - 1);
                float fx = (xl >= WW - 1) ? 0.0f : (cx - (float)xl);
                float hx = 1.0f - fx, lx = fx;
                int cx0 = xl - col0, cx1 = xh - col0;

                float v00 = tch[ry0 * PITCH + cx0];
                float v01 = tch[ry0 * PITCH + cx1];
                float v10 = tch[ry1 * PITCH + cx0];
                float v11 = tch[ry1 * PITCH + cx1];

                float v = hy * (hx * v00 + lx * v01) + ly * (hx * v10 + lx * v11);
                if (vy && vx) acc += v;
            }
        }
        out[((size_t)n * CC + c0 + ch) * (PH * PW) + p] = acc * (1.0f / (SR * SR));
    }
}

extern "C" void kernel_launch(void* const* d_in, const int* in_sizes, int n_in,
                              void* d_out, int out_size, void* d_ws, size_t ws_size,
                              hipStream_t stream) {
    const float* features = (const float*)d_in[0];
    const float* rois     = (const float*)d_in[1];
    float*       out      = (float*)d_out;

    int N = in_sizes[1] / 5;  // 512 rois

    dim3 grid(N, CC / CPC);   // 512 x 64 blocks
    roi_align_lds<<<grid, 256, 0, stream>>>(features, rois, out);
}

// Round 3
// 182.517 us; speedup vs baseline: 1.3455x; 1.3455x over previous
//
#include <hip/hip_runtime.h>

#define PH 7
#define PW 7
#define NB 49            // PH*PW
#define SSCALE 0.0625f
#define CC 256
#define HH 200
#define WW 200
#define HWSZ (HH * WW)

#define CPG 4            // channels per LDS group
#define NG 4             // groups per block -> 16 channels/block
#define SLAB (CPG * NG)
#define TH_MAX 40        // max footprint span (rows or cols)
#define PITCH 41         // +1 pad to break bank strides
#define TILE (TH_MAX * PITCH)

__global__ __launch_bounds__(256, 4) void roi_align_v3(
    const float* __restrict__ features, const float* __restrict__ rois,
    float* __restrict__ out)
{
    __shared__ float tile[CPG * TILE];   // 26.24 KB

    const int n      = blockIdx.x;
    const int c_base = blockIdx.y * SLAB;
    const int t      = threadIdx.x;

    // ---- roi params (uniform; rois loads broadcast) ----
    const float* r = rois + (size_t)n * 5;
    const int   b  = (int)r[0];
    const float x1 = r[1] * SSCALE;
    const float y1 = r[2] * SSCALE;
    const float x2 = r[3] * SSCALE;
    const float y2 = r[4] * SSCALE;

    const float bin_w = fmaxf(x2 - x1, 1.0f) * (1.0f / PW);
    const float bin_h = fmaxf(y2 - y1, 1.0f) * (1.0f / PH);

    // footprint: samples span [0.25*bin, 6.75*bin] past (x1,y1)
    const float yA = y1 + 0.25f * bin_h, yB = y1 + 6.75f * bin_h;
    const float xA = x1 + 0.25f * bin_w, xB = x1 + 6.75f * bin_w;

    const int row0 = min((int)floorf(fmaxf(yA, 0.f)), HH - 1);
    const int row1 = min(min((int)floorf(fmaxf(yB, 0.f)), HH - 1) + 1, HH - 1);
    const int th   = row1 - row0 + 1;                 // <= 40
    const int col0 = min((int)floorf(fmaxf(xA, 0.f)), WW - 1);
    const int col1 = min(min((int)floorf(fmaxf(xB, 0.f)), WW - 1) + 1, WW - 1);
    const int tw   = col1 - col0 + 1;                 // <= 40

    const int nri = (th + 7) >> 3;    // row iters, stride 8 (uniform)
    const int nci = (tw + 31) >> 5;   // col iters, stride 32 (uniform, 1..2)

    const int cc  = t & 31;           // staging col lane
    const int rr0 = t >> 5;           // staging row lane 0..7

    // ---- per-thread bin coordinates & weights: computed ONCE ----
    const bool is_comp = (t < CPG * NB);
    int   ch_in_g = 0, bin = 0;
    int   ryo[2][2], cxo[2][2];       // LDS offsets: [sample][lo/hi]
    float wy[2][2], wx[2][2];         // weights with validity folded in
    if (is_comp) {
        ch_in_g = t / NB;             // const divisor -> magic mul
        bin     = t - ch_in_g * NB;
        int ph  = bin / PW;
        int pw  = bin - ph * PW;
        #pragma unroll
        for (int i = 0; i < 2; ++i) {
            float sfrac = i ? 0.75f : 0.25f;

            float y  = y1 + ((float)ph + sfrac) * bin_h;
            bool  vy = (y >= -1.f) && (y <= (float)HH);
            float cy = fmaxf(y, 0.f);
            int   yl = min((int)floorf(cy), HH - 1);
            int   yh = min(yl + 1, HH - 1);
            float fy = (yl >= HH - 1) ? 0.f : (cy - (float)yl);
            wy[i][0] = vy ? (1.f - fy) : 0.f;
            wy[i][1] = vy ? fy : 0.f;
            ryo[i][0] = (yl - row0) * PITCH;
            ryo[i][1] = (yh - row0) * PITCH;

            float x  = x1 + ((float)pw + sfrac) * bin_w;
            bool  vx = (x >= -1.f) && (x <= (float)WW);
            float cx = fmaxf(x, 0.f);
            int   xl = min((int)floorf(cx), WW - 1);
            int   xh = min(xl + 1, WW - 1);
            float fx = (xl >= WW - 1) ? 0.f : (cx - (float)xl);
            wx[i][0] = vx ? (1.f - fx) : 0.f;
            wx[i][1] = vx ? fx : 0.f;
            cxo[i][0] = xl - col0;
            cxo[i][1] = xh - col0;
        }
    }

    const float* fb = features + ((size_t)b * CC + c_base) * HWSZ
                    + (size_t)row0 * WW + col0;

    for (int g = 0; g < NG; ++g) {
        const float* fg = fb + (size_t)(g * CPG) * HWSZ;

        // ---- stage CPG channels (shift/mask addressing only) ----
        for (int i = 0; i < nri; ++i) {
            int rr  = rr0 + (i << 3);
            int rrc = min(rr, th - 1);
            for (int j = 0; j < nci; ++j) {
                int col  = cc + (j << 5);
                int colc = min(col, tw - 1);
                int gofs = rrc * WW + colc;
                // 4 independent loads in flight
                float v0 = fg[0 * HWSZ + gofs];
                float v1 = fg[1 * HWSZ + gofs];
                float v2 = fg[2 * HWSZ + gofs];
                float v3 = fg[3 * HWSZ + gofs];
                if (rr < th && col < tw) {
                    int o = rrc * PITCH + colc;
                    tile[0 * TILE + o] = v0;
                    tile[1 * TILE + o] = v1;
                    tile[2 * TILE + o] = v2;
                    tile[3 * TILE + o] = v3;
                }
            }
        }
        __syncthreads();

        // ---- compute: 16 ds_reads + ~12 FMA per thread ----
        if (is_comp) {
            const float* tch = &tile[ch_in_g * TILE];
            float acc = 0.f;
            #pragma unroll
            for (int iy = 0; iy < 2; ++iy) {
                #pragma unroll
                for (int ix = 0; ix < 2; ++ix) {
                    float v00 = tch[ryo[iy][0] + cxo[ix][0]];
                    float v01 = tch[ryo[iy][0] + cxo[ix][1]];
                    float v10 = tch[ryo[iy][1] + cxo[ix][0]];
                    float v11 = tch[ryo[iy][1] + cxo[ix][1]];
                    acc += wy[iy][0] * (wx[ix][0] * v00 + wx[ix][1] * v01)
                         + wy[iy][1] * (wx[ix][0] * v10 + wx[ix][1] * v11);
                }
            }
            out[((size_t)n * CC + c_base + g * CPG + ch_in_g) * NB + bin] =
                acc * 0.25f;
        }
        __syncthreads();   // WAR guard before next group's staging
    }
}

extern "C" void kernel_launch(void* const* d_in, const int* in_sizes, int n_in,
                              void* d_out, int out_size, void* d_ws, size_t ws_size,
                              hipStream_t stream) {
    const float* features = (const float*)d_in[0];
    const float* rois     = (const float*)d_in[1];
    float*       out      = (float*)d_out;

    int N = in_sizes[1] / 5;          // 512 rois

    dim3 grid(N, CC / SLAB);          // 512 x 16 blocks
    roi_align_v3<<<grid, 256, 0, stream>>>(features, rois, out);
}